// Round 6
// baseline (131.381 us; speedup 1.0000x reference)
//
#include <hip/hip_runtime.h>

// Problem constants (fixed by setup_inputs)
#define D        256     // feature dim
#define NPG      512     // nodes per graph
#define BG       128     // num graphs
#define KSEL     256     // k = ceil(0.5 * 512)
#define EPG      4096    // edges per graph
#define NN       (BG * NPG)      // 65536 nodes
#define ET       (BG * EPG)      // 524288 edges

// Kernel A: p = x @ w_rel, r = x @ w_root (one wave per node).
// Full-chip stream of the 64 MB x — BW-bound, ~11 us.
// Blocks 0..BG-1 also zero the per-graph pool accumulators (stream order
// guarantees this completes before kernel B's atomics).
__global__ __launch_bounds__(256) void k_proj_scores(
        const float* __restrict__ x,
        const float* __restrict__ w_rel, const float* __restrict__ w_root,
        float* __restrict__ p, float* __restrict__ r,
        float* __restrict__ pool) {
    int tid  = threadIdx.x;
    if (blockIdx.x < BG) pool[(size_t)blockIdx.x * D + tid] = 0.f;
    int wave = tid >> 6, lane = tid & 63;
    int node = blockIdx.x * 4 + wave;

    const float4* x4  = (const float4*)(x + (size_t)node * D);
    float4 xv = x4[lane];
    float4 wr = ((const float4*)w_rel)[lane];
    float4 wo = ((const float4*)w_root)[lane];
    float pv = xv.x * wr.x + xv.y * wr.y + xv.z * wr.z + xv.w * wr.w;
    float rv = xv.x * wo.x + xv.y * wo.y + xv.z * wo.z + xv.w * wo.w;
    #pragma unroll
    for (int off = 32; off; off >>= 1) {
        pv += __shfl_xor(pv, off, 64);
        rv += __shfl_xor(rv, off, 64);
    }
    if (lane == 0) { p[node] = pv; r[node] = rv; }
}

// Kernel B: FOUR blocks per graph (512 blocks = 2 blocks/CU, so co-resident
// blocks overlap each other's barriers). Each quarter-block duplicates the
// cheap whole-graph phases (p-load, edge scatter, tanh) and splits the
// latency-heavy ones: ranks 128 nodes, pools its own selected rows (~64),
// then atomically accumulates its 256-float pooled partial into pool[b].
// No per-block fences; kernel C provides device-scope ordering once.
__global__ __launch_bounds__(1024) void k_select_pool(
        const float* __restrict__ x, const int* __restrict__ ei,
        const float* __restrict__ p, const float* __restrict__ r,
        const float* __restrict__ b_rel,
        float* __restrict__ pool) {
    __shared__ __align__(16) float s_p[NPG];
    __shared__ __align__(16) float s_agg[NPG];
    __shared__ __align__(16) float s_val[NPG];
    __shared__ int   s_cnt[1024];
    __shared__ int   s_selid[128];
    __shared__ __align__(16) float s_selv[128];
    __shared__ __align__(16) float s_red[16][D];
    __shared__ int   s_nsel;

    int blk = blockIdx.x;
    int b = blk >> 2, quarter = blk & 3;
    int tid = threadIdx.x, wave = tid >> 6, lane = tid & 63;
    int base = b * NPG;

    if (tid < NPG) { s_p[tid] = p[base + tid]; s_agg[tid] = 0.f; }
    if (tid == 0)  s_nsel = 0;
    __syncthreads();

    // ---- Edge scatter (duplicated per quarter-block): agg[dst] += p[src]
    {
        const int* src = ei + (size_t)b * EPG;
        const int* dst = ei + ET + (size_t)b * EPG;
        #pragma unroll
        for (int e = tid; e < EPG; e += 1024)
            atomicAdd(&s_agg[dst[e] - base], s_p[src[e] - base]);
    }
    __syncthreads();

    // ---- score = tanh(agg + b_rel + r)  (all 512 nodes, duplicated)
    if (tid < NPG)
        s_val[tid] = tanhf(s_agg[tid] + b_rel[0] + r[base + tid]);
    __syncthreads();

    // ---- Exact rank for MY 128 nodes: 8 threads/node, 64 scores each.
    // rank(j) = #{i : s_i > s_j or (s_i == s_j and i < j)}
    {
        int jj = tid & 127;
        int j  = quarter * 128 + jj;             // node this thread helps rank
        int q  = tid >> 7;                       // 0..7 -> eighth of scores
        float sv = s_val[j];
        const float4* v4 = (const float4*)s_val + q * 16;
        int i0b = q * 64;
        int c = 0;
        #pragma unroll
        for (int t = 0; t < 16; ++t) {           // 16 float4 = 64 scores
            float4 o = v4[t];                    // wave-uniform b128 broadcast
            int i0 = i0b + t * 4;
            c += (o.x > sv) || (o.x == sv && (i0 + 0) < j);
            c += (o.y > sv) || (o.y == sv && (i0 + 1) < j);
            c += (o.z > sv) || (o.z == sv && (i0 + 2) < j);
            c += (o.w > sv) || (o.w == sv && (i0 + 3) < j);
        }
        s_cnt[tid] = c;
    }
    __syncthreads();
    if (tid < 128) {
        int rank = 0;
        #pragma unroll
        for (int m = 0; m < 8; ++m) rank += s_cnt[tid + m * 128];
        if (rank < KSEL) {                       // top-KSEL overall (total order)
            int pos = atomicAdd(&s_nsel, 1);
            s_selid[pos] = quarter * 128 + tid;
            s_selv[pos]  = s_val[quarter * 128 + tid];
        }
    }
    __syncthreads();
    int nsel = s_nsel;                           // 0..128, quarters sum to KSEL

    // ---- Weighted pool over MY selected rows (L3-warm gather).
    {
        float4 acc = {0.f, 0.f, 0.f, 0.f};
        for (int s = wave; s < nsel; s += 16) {  // wave-uniform trip count
            int row = s_selid[s];                // wave-uniform broadcast
            float v = s_selv[s];
            float4 xv = ((const float4*)(x + (size_t)(base + row) * D))[lane];
            acc.x += v * xv.x; acc.y += v * xv.y;
            acc.z += v * xv.z; acc.w += v * xv.w;
        }
        ((float4*)s_red[wave])[lane] = acc;
    }
    __syncthreads();
    if (tid < D) {
        float s = 0.f;
        #pragma unroll
        for (int w = 0; w < 16; ++w) s += s_red[w][tid];
        atomicAdd(&pool[(size_t)b * D + tid], s);   // merge quarter partials
    }
}

// Kernel C: out[b,f] = b_proj[f] + (1/k) * sum_kk pool[b,kk] * w_proj[kk,f]
// One block per graph, 1024 threads (4-way split over kk + LDS reduce).
// w_proj (256 KB) is L2-hot across blocks.
__global__ __launch_bounds__(1024) void k_project(
        const float* __restrict__ pool,
        const float* __restrict__ w_proj, const float* __restrict__ b_proj,
        float* __restrict__ out) {
    __shared__ __align__(16) float s_pool[D];
    __shared__ __align__(16) float s_red[4][D];
    int b = blockIdx.x, tid = threadIdx.x;
    if (tid < D) s_pool[tid] = pool[(size_t)b * D + tid];
    __syncthreads();
    {
        int f = tid & (D - 1);
        int q = tid >> 8;                        // 0..3, quarter of kk
        const float4* pool4 = (const float4*)s_pool + q * 16;
        const float* wp = w_proj + (size_t)(q * 64) * D + f;
        float acc = 0.f;
        #pragma unroll
        for (int t = 0; t < 16; ++t) {
            float4 pv = pool4[t];                // wave-uniform b128 broadcast
            acc += pv.x * wp[(t * 4 + 0) * D];
            acc += pv.y * wp[(t * 4 + 1) * D];
            acc += pv.z * wp[(t * 4 + 2) * D];
            acc += pv.w * wp[(t * 4 + 3) * D];
        }
        s_red[q][f] = acc;
    }
    __syncthreads();
    if (tid < D)
        out[(size_t)b * D + tid] = b_proj[tid] +
            (s_red[0][tid] + s_red[1][tid] + s_red[2][tid] + s_red[3][tid]) * (1.0f / KSEL);
}

extern "C" void kernel_launch(void* const* d_in, const int* in_sizes, int n_in,
                              void* d_out, int out_size, void* d_ws, size_t ws_size,
                              hipStream_t stream) {
    const float* x      = (const float*)d_in[0];
    const int*   ei     = (const int*)d_in[1];
    // d_in[2] = batch (unused: contiguous equal-size graphs)
    // d_in[3] = num_graphs (hardcoded BG)
    const float* w_rel  = (const float*)d_in[4];
    const float* b_rel  = (const float*)d_in[5];
    const float* w_root = (const float*)d_in[6];
    const float* w_proj = (const float*)d_in[7];
    const float* b_proj = (const float*)d_in[8];
    float* out = (float*)d_out;

    float* p    = (float*)d_ws;                  // NN floats
    float* r    = p + NN;                        // NN floats
    float* pool = r + NN;                        // BG*D floats (zeroed by K1)

    k_proj_scores<<<NN / 4, 256, 0, stream>>>(x, w_rel, w_root, p, r, pool);
    k_select_pool<<<4 * BG, 1024, 0, stream>>>(x, ei, p, r, b_rel, pool);
    k_project<<<BG, 1024, 0, stream>>>(pool, w_proj, b_proj, out);
}

// Round 7
// 128.194 us; speedup vs baseline: 1.0249x; 1.0249x over previous
//
#include <hip/hip_runtime.h>

// Problem constants (fixed by setup_inputs)
#define D        256     // feature dim
#define NPG      512     // nodes per graph
#define BG       128     // num graphs
#define KSEL     256     // k = ceil(0.5 * 512)
#define EPG      4096    // edges per graph
#define NN       (BG * NPG)      // 65536 nodes
#define ET       (BG * EPG)      // 524288 edges

// Kernel A: p = x @ w_rel, r = x @ w_root (one wave per node).
// Full-chip stream of the 64 MB x — BW-bound, ~11 us (roofline).
__global__ __launch_bounds__(256) void k_proj_scores(
        const float* __restrict__ x,
        const float* __restrict__ w_rel, const float* __restrict__ w_root,
        float* __restrict__ p, float* __restrict__ r) {
    int tid  = threadIdx.x;
    int wave = tid >> 6, lane = tid & 63;
    int node = blockIdx.x * 4 + wave;

    const float4* x4  = (const float4*)(x + (size_t)node * D);
    float4 xv = x4[lane];
    float4 wr = ((const float4*)w_rel)[lane];
    float4 wo = ((const float4*)w_root)[lane];
    float pv = xv.x * wr.x + xv.y * wr.y + xv.z * wr.z + xv.w * wr.w;
    float rv = xv.x * wo.x + xv.y * wo.y + xv.z * wo.z + xv.w * wo.w;
    #pragma unroll
    for (int off = 32; off; off >>= 1) {
        pv += __shfl_xor(pv, off, 64);
        rv += __shfl_xor(rv, off, 64);
    }
    if (lane == 0) { p[node] = pv; r[node] = rv; }
}

// Kernel B: TWO blocks per graph (256 blocks, full chip). Each half-block
// duplicates the cheap whole-graph phases (p-load, edge scatter, tanh —
// duplication is the price of per-block ranking) and splits the expensive
// ones: ranks its 256 nodes against all 512 scores, pools its own selected
// rows (~128, L3-warm), and writes the RAW pooled partial (256 floats).
// NO per-block matvec (that cost 64 MB of w_proj L2 reads in round 5) and
// NO cross-block fences — kernel C merges at the kernel boundary.
__global__ __launch_bounds__(1024) void k_select_pool(
        const float* __restrict__ x, const int* __restrict__ ei,
        const float* __restrict__ p, const float* __restrict__ r,
        const float* __restrict__ b_rel,
        float* __restrict__ ppart) {
    __shared__ __align__(16) float s_p[NPG];
    __shared__ __align__(16) float s_agg[NPG];
    __shared__ __align__(16) float s_val[NPG];
    __shared__ int   s_cnt4[1024];
    __shared__ int   s_selid[256];
    __shared__ __align__(16) float s_selv[256];
    __shared__ __align__(16) float s_red[16][D];
    __shared__ int   s_nsel;

    int blk = blockIdx.x;
    int b = blk >> 1, half = blk & 1;
    int tid = threadIdx.x, wave = tid >> 6, lane = tid & 63;
    int base = b * NPG;

    if (tid < NPG) { s_p[tid] = p[base + tid]; s_agg[tid] = 0.f; }
    if (tid == 0)  s_nsel = 0;
    __syncthreads();

    // ---- Edge scatter (duplicated per half-block): agg[dst] += p[src]
    {
        const int* src = ei + (size_t)b * EPG;
        const int* dst = ei + ET + (size_t)b * EPG;
        #pragma unroll
        for (int e = tid; e < EPG; e += 1024)
            atomicAdd(&s_agg[dst[e] - base], s_p[src[e] - base]);
    }
    __syncthreads();

    // ---- score = tanh(agg + b_rel + r)  (all 512 nodes, duplicated)
    if (tid < NPG)
        s_val[tid] = tanhf(s_agg[tid] + b_rel[0] + r[base + tid]);
    __syncthreads();

    // ---- Exact rank for MY 256 nodes: 4 threads/node, 128 scores each.
    // rank(j) = #{i : s_i > s_j or (s_i == s_j and i < j)}
    {
        int j = half * 256 + (tid & 255);        // node this thread helps rank
        int q = tid >> 8;                        // 0..3 -> quarter of scores
        float sv = s_val[j];
        const float4* v4 = (const float4*)s_val + q * 32;
        int i0b = q * 128;
        int c = 0;
        #pragma unroll 8
        for (int t = 0; t < 32; ++t) {           // 32 float4 = 128 scores
            float4 o = v4[t];                    // wave-uniform b128 broadcast
            int i0 = i0b + t * 4;
            c += (o.x > sv) || (o.x == sv && (i0 + 0) < j);
            c += (o.y > sv) || (o.y == sv && (i0 + 1) < j);
            c += (o.z > sv) || (o.z == sv && (i0 + 2) < j);
            c += (o.w > sv) || (o.w == sv && (i0 + 3) < j);
        }
        s_cnt4[tid] = c;
    }
    __syncthreads();
    if (tid < 256) {
        int rank = s_cnt4[tid] + s_cnt4[tid + 256] + s_cnt4[tid + 512] + s_cnt4[tid + 768];
        if (rank < KSEL) {                       // top-KSEL overall (total order)
            int pos = atomicAdd(&s_nsel, 1);
            s_selid[pos] = half * 256 + tid;
            s_selv[pos]  = s_val[half * 256 + tid];
        }
    }
    __syncthreads();
    int nsel = s_nsel;                           // 0..256, halves sum to KSEL

    // ---- Weighted pool over MY selected rows (L3-warm gather).
    {
        float4 acc = {0.f, 0.f, 0.f, 0.f};
        for (int s = wave; s < nsel; s += 16) {  // wave-uniform trip count
            int row = s_selid[s];                // wave-uniform broadcast
            float v = s_selv[s];
            float4 xv = ((const float4*)(x + (size_t)(base + row) * D))[lane];
            acc.x += v * xv.x; acc.y += v * xv.y;
            acc.z += v * xv.z; acc.w += v * xv.w;
        }
        ((float4*)s_red[wave])[lane] = acc;
    }
    __syncthreads();

    // ---- Write RAW pooled partial (no matvec here).
    if (tid < D) {
        float s = 0.f;
        #pragma unroll
        for (int w = 0; w < 16; ++w) s += s_red[w][tid];
        ppart[(size_t)blk * D + tid] = s;
    }
}

// Kernel C: pool[b] = ppart[2b] + ppart[2b+1];
// out[b,f] = b_proj[f] + (1/k) * sum_kk pool[kk] * w_proj[kk,f].
// One block per graph, 1024 threads (4-way kk-split + LDS reduce).
// w_proj traffic: 128 blocks x 256 KB = 32 MB, L2-hot. ~2 us.
__global__ __launch_bounds__(1024) void k_project(
        const float* __restrict__ ppart,
        const float* __restrict__ w_proj, const float* __restrict__ b_proj,
        float* __restrict__ out) {
    __shared__ __align__(16) float s_pool[D];
    __shared__ __align__(16) float s_red[4][D];
    int b = blockIdx.x, tid = threadIdx.x;
    if (tid < D)
        s_pool[tid] = ppart[(size_t)(2 * b) * D + tid]
                    + ppart[(size_t)(2 * b + 1) * D + tid];
    __syncthreads();
    {
        int f = tid & (D - 1);
        int q = tid >> 8;                        // 0..3, quarter of kk
        const float4* pool4 = (const float4*)s_pool + q * 16;
        const float* wp = w_proj + (size_t)(q * 64) * D + f;
        float acc = 0.f;
        #pragma unroll
        for (int t = 0; t < 16; ++t) {
            float4 pv = pool4[t];                // wave-uniform b128 broadcast
            acc += pv.x * wp[(t * 4 + 0) * D];
            acc += pv.y * wp[(t * 4 + 1) * D];
            acc += pv.z * wp[(t * 4 + 2) * D];
            acc += pv.w * wp[(t * 4 + 3) * D];
        }
        s_red[q][f] = acc;
    }
    __syncthreads();
    if (tid < D)
        out[(size_t)b * D + tid] = b_proj[tid] +
            (s_red[0][tid] + s_red[1][tid] + s_red[2][tid] + s_red[3][tid]) * (1.0f / KSEL);
}

extern "C" void kernel_launch(void* const* d_in, const int* in_sizes, int n_in,
                              void* d_out, int out_size, void* d_ws, size_t ws_size,
                              hipStream_t stream) {
    const float* x      = (const float*)d_in[0];
    const int*   ei     = (const int*)d_in[1];
    // d_in[2] = batch (unused: contiguous equal-size graphs)
    // d_in[3] = num_graphs (hardcoded BG)
    const float* w_rel  = (const float*)d_in[4];
    const float* b_rel  = (const float*)d_in[5];
    const float* w_root = (const float*)d_in[6];
    const float* w_proj = (const float*)d_in[7];
    const float* b_proj = (const float*)d_in[8];
    float* out = (float*)d_out;

    float* p     = (float*)d_ws;                 // NN floats
    float* r     = p + NN;                       // NN floats
    float* ppart = r + NN;                       // 2*BG*D floats

    k_proj_scores<<<NN / 4, 256, 0, stream>>>(x, w_rel, w_root, p, r);
    k_select_pool<<<2 * BG, 1024, 0, stream>>>(x, ei, p, r, b_rel, ppart);
    k_project<<<BG, 1024, 0, stream>>>(ppart, w_proj, b_proj, out);
}